// Round 5
// baseline (136.880 us; speedup 1.0000x reference)
//
#include <hip/hip_runtime.h>
#include <hip/hip_bf16.h>
#include <hip/hip_fp16.h>

// Tables: ESP/EIP/ECS/ECI = exp(-logit) in FP16 (fp8 reverted in R5: decode
// instrs cost more than bytes save — conc tables are L2-resident).
// Edge per channel: sigma(a)-sigma(b) = (B-A)/(A*B), A=1+es*cs, B=1+ei*ci via
// v_pk_fma; fraction pair-tree 8->4->2->1 in F32 (v_fma_mix) -> 1 rcp/lane*k.
// R6: edge kernel is LATENCY-bound (R4 calib: issue time ~13.5us vs 43.3us
// wall; VGPR=32 blocked load batching). Each 16-lane group now owns TWO
// sequential edges (8 edges/wave): all ~24 gathers issued before compute ->
// 2x independent load streams/wave + in-wave compute/load overlap (T14).
// 32-bit gather addressing (idx<<7 + li*8). DPP butterfly reduce — no LDS.
// Timed-region: 2x 256MiB harness poison fills ~90us structural;
// controllable = edge (~43us R4) + proj ~2us.
constexpr int EDGES = 250000;
constexpr int EMB   = 64;
constexpr int CNUM  = 128;
constexpr int NSTU  = 10000;
constexpr int NITEM = 50000;
constexpr int NCONC = 2048;

constexpr float NEG_LOG2E = -1.44269504088896340736f;

// proj job space: one wave per 16-row strip (conc strips: one wave per table)
constexpr int STU_JOBS  = NSTU  / 16;            // 625
constexpr int ITEM_JOBS = NITEM / 16;            // 3125
constexpr int CONC_JOBS = (NCONC / 16) * 2;      // 256
constexpr int NJOBS     = STU_JOBS + ITEM_JOBS + CONC_JOBS;  // 4006
constexpr int PROJ_BLKS = (NJOBS + 3) / 4;

constexpr int EDGE_WAVES = EDGES / 8;            // 31250 (8 edges/wave)
constexpr int EDGE_BLKS  = (EDGE_WAVES + 3) / 4; // 7813

typedef _Float16 h8 __attribute__((ext_vector_type(8)));
typedef _Float16 h4 __attribute__((ext_vector_type(4)));
typedef _Float16 h2 __attribute__((ext_vector_type(2)));
typedef float    f32x4 __attribute__((ext_vector_type(4)));

__device__ __forceinline__ h2 cvt2(float a, float b) {
#if __has_builtin(__builtin_amdgcn_cvt_pkrtz)
    return __builtin_bit_cast(h2, __builtin_amdgcn_cvt_pkrtz(a, b));
#else
    h2 r; r[0] = (_Float16)a; r[1] = (_Float16)b; return r;
#endif
}

__device__ __forceinline__ h8 pack8(float4 lo, float4 hi) {
    const h2 a = cvt2(lo.x, lo.y);
    const h2 b = cvt2(lo.z, lo.w);
    const h2 c = cvt2(hi.x, hi.y);
    const h2 d = cvt2(hi.z, hi.w);
    const h4 ab = __builtin_shufflevector(a, b, 0, 1, 2, 3);
    const h4 cd = __builtin_shufflevector(c, d, 0, 1, 2, 3);
    return __builtin_shufflevector(ab, cd, 0, 1, 2, 3, 4, 5, 6, 7);
}

// x += dpp-permuted x (full-rate VALU, no LDS pipe)
template <int CTRL>
__device__ __forceinline__ float dppadd(float x) {
    return x + __int_as_float(__builtin_amdgcn_update_dpp(
        0, __float_as_int(x), CTRL, 0xf, 0xf, true));
}

// ---- projection via MFMA: O[r,c] = exp(-dot(F[r,:], W[c, wcol:wcol+64])) ---
__global__ __launch_bounds__(256) void proj_mfma(
        const float* __restrict__ stuF, const float* __restrict__ itemF,
        const float* __restrict__ concF,
        const float* __restrict__ W_stu, const float* __restrict__ W_item,
        const float* __restrict__ w_pred,
        _Float16* __restrict__ ESP, _Float16* __restrict__ EIP,
        _Float16* __restrict__ ECS, _Float16* __restrict__ ECI,
        _Float16* __restrict__ WH) {
    const int tid  = threadIdx.x;
    const int lane = tid & 63;
    const int job  = blockIdx.x * 4 + (tid >> 6);
    if (job >= NJOBS) return;

    if (job == 0) {  // one wave converts w_pred (128 f32) to fp16 once
        const float2 wv2 = ((const float2*)w_pred)[lane];
        h2 wh; wh[0] = (_Float16)wv2.x; wh[1] = (_Float16)wv2.y;
        *(h2*)(WH + 2 * lane) = wh;
    }

    const float* F; const float* W; _Float16* O; int strip, wcol;
    if (job < STU_JOBS) {
        F = stuF;  W = W_stu;  O = ESP; strip = job; wcol = 0;
    } else if (job < STU_JOBS + ITEM_JOBS) {
        F = itemF; W = W_item; O = EIP; strip = job - STU_JOBS; wcol = 0;
    } else {
        const int g = job - STU_JOBS - ITEM_JOBS;
        F = concF; W = (g & 1) ? W_item : W_stu; O = (g & 1) ? ECI : ECS;
        strip = g >> 1; wcol = EMB;
    }

    const int m = lane & 15;       // A row / B channel / D col
    const int q = lane >> 4;       // quad
    const int row = strip * 16 + m;

    const float4* fa = (const float4*)(F + (size_t)row * EMB + q * 8);
    const float4* fb = (const float4*)(F + (size_t)row * EMB + 32 + q * 8);
    const h8 A0 = pack8(fa[0], fa[1]);
    const h8 A1 = pack8(fb[0], fb[1]);

    const int orow = strip * 16 + q * 4;

#pragma unroll
    for (int ct = 0; ct < 8; ++ct) {
        const int ch = ct * 16 + m;
        const float* wr = W + (size_t)ch * (2 * EMB) + wcol;
        const float4* wb0 = (const float4*)(wr + q * 8);
        const float4* wb1 = (const float4*)(wr + 32 + q * 8);
        const h8 B0 = pack8(wb0[0], wb0[1]);
        const h8 B1 = pack8(wb1[0], wb1[1]);

        f32x4 acc = {0.f, 0.f, 0.f, 0.f};
        acc = __builtin_amdgcn_mfma_f32_16x16x32_f16(A0, B0, acc, 0, 0, 0);
        acc = __builtin_amdgcn_mfma_f32_16x16x32_f16(A1, B1, acc, 0, 0, 0);

#pragma unroll
        for (int r = 0; r < 4; ++r) {
            const float e = __builtin_amdgcn_exp2f(acc[r] * NEG_LOG2E);
            O[(unsigned)(orow + r) * CNUM + ct * 16 + m] = (_Float16)e;
        }
    }
}

__device__ __forceinline__ float sigm(float x) {
    return __builtin_amdgcn_rcpf(1.f + __builtin_amdgcn_exp2f(x * NEG_LOG2E));
}

// one k-iteration: 8-channel fraction sum, 1 rcp
__device__ __forceinline__ float edge_k(h8 es, h8 cs, h8 ei, h8 ci, h8 w8) {
    const _Float16 O1 = (_Float16)1.f;
    const h8 ONE = {O1, O1, O1, O1, O1, O1, O1, O1};
    const h8 Aq = es * cs + ONE;       // 1+t        (v_pk_fma)
    const h8 Bq = ei * ci + ONE;       // 1+u        (v_pk_fma)
    const h8 dn = Aq * Bq;             // den, <=65504 till ~12-sigma
    const h8 nm = w8 * (Bq - Aq);      // w*(u-t)
    // pair-tree in F32 (v_fma_mix reads fp16 ops directly): 8->4->2->1
    float N1[4], D1[4];
#pragma unroll
    for (int i = 0; i < 4; ++i) {
        N1[i] = (float)nm[i] * (float)dn[i + 4]
              + (float)nm[i + 4] * (float)dn[i];
        D1[i] = (float)dn[i] * (float)dn[i + 4];
    }
    const float N2a = N1[0] * D1[2] + N1[2] * D1[0];
    const float N2b = N1[1] * D1[3] + N1[3] * D1[1];
    const float D2a = D1[0] * D1[2];
    const float D2b = D1[1] * D1[3];
    const float N3 = N2a * D2b + N2b * D2a;
    const float D3 = D2a * D2b;        // prod of 8 dens; f32-safe
    return N3 * __builtin_amdgcn_rcpf(D3);
}

// ---- edge phase: 8 edges/wave (2 per 16-lane group), lane owns 8 ch ------
__global__ __launch_bounds__(256) void edge_kernel(
        const int*  __restrict__ stu_idx,
        const int*  __restrict__ item_idx,
        const int4* __restrict__ conc_idx,
        const _Float16* __restrict__ ESP,
        const _Float16* __restrict__ EIP,
        const _Float16* __restrict__ ECS,
        const _Float16* __restrict__ ECI,
        const _Float16* __restrict__ WH,
        const float* __restrict__ b_pred,
        float* __restrict__ out) {
    const int lane = threadIdx.x & 63;
    const int wvg  = (blockIdx.x * blockDim.x + threadIdx.x) >> 6;
    if (wvg >= EDGE_WAVES) return;   // wave-uniform guard (tail block)
    const int sub  = lane >> 4;      // group within wave 0..3
    const int li   = lane & 15;      // lane within group; owns ch li*8..+7
    const unsigned co = (unsigned)(li * 8);
    const int e0 = wvg * 8 + sub;    // first edge of this group
    const int e1 = e0 + 4;           // second edge

    // ---- issue ALL gathers before any compute (latency overlap) ----
    const int s0  = stu_idx[e0],  s1  = stu_idx[e1];
    const int it0 = item_idx[e0], it1 = item_idx[e1];
    const int4 c40 = conc_idx[e0], c41 = conc_idx[e1];

    const h8 es0 = *(const h8*)(ESP + (((unsigned)s0  << 7) + co));
    const h8 ei0 = *(const h8*)(EIP + (((unsigned)it0 << 7) + co));
    const h8 es1 = *(const h8*)(ESP + (((unsigned)s1  << 7) + co));
    const h8 ei1 = *(const h8*)(EIP + (((unsigned)it1 << 7) + co));
    const h8 w8  = *(const h8*)(WH + co);   // shared by both edges
    const float b = b_pred[0];

    const int ck0[4] = {c40.x, c40.y, c40.z, c40.w};
    const int ck1[4] = {c41.x, c41.y, c41.z, c41.w};
    h8 cs0[4], ci0[4], cs1[4], ci1[4];
#pragma unroll
    for (int k = 0; k < 4; ++k) {
        const unsigned o0 = ((unsigned)ck0[k] << 7) + co;
        cs0[k] = *(const h8*)(ECS + o0);
        ci0[k] = *(const h8*)(ECI + o0);
    }
#pragma unroll
    for (int k = 0; k < 4; ++k) {
        const unsigned o1 = ((unsigned)ck1[k] << 7) + co;
        cs1[k] = *(const h8*)(ECS + o1);
        ci1[k] = *(const h8*)(ECI + o1);
    }

    // ---- compute: edge0 -> p[0..3], edge1 -> p[4..7] ----
    float p[8];
#pragma unroll
    for (int k = 0; k < 4; ++k) p[k]     = edge_k(es0, cs0[k], ei0, ci0[k], w8);
#pragma unroll
    for (int k = 0; k < 4; ++k) p[k + 4] = edge_k(es1, cs1[k], ei1, ci1[k], w8);

    // 16-lane sum via DPP butterfly; xor-basis {1,2,7,15} spans the group.
#pragma unroll
    for (int j = 0; j < 8; ++j) p[j] = dppadd<0xB1>(p[j]);   // quad_perm xor1
#pragma unroll
    for (int j = 0; j < 8; ++j) p[j] = dppadd<0x4E>(p[j]);   // quad_perm xor2
#pragma unroll
    for (int j = 0; j < 8; ++j) p[j] = dppadd<0x141>(p[j]);  // row_half_mirror
#pragma unroll
    for (int j = 0; j < 8; ++j) p[j] = dppadd<0x140>(p[j]);  // row_mirror

    const float r0 = 0.25f * (sigm(p[0] + b) + sigm(p[1] + b) +
                              sigm(p[2] + b) + sigm(p[3] + b));
    const float r1 = 0.25f * (sigm(p[4] + b) + sigm(p[5] + b) +
                              sigm(p[6] + b) + sigm(p[7] + b));
    if (li == 0) { out[e0] = r0; out[e1] = r1; }
}

extern "C" void kernel_launch(void* const* d_in, const int* in_sizes, int n_in,
                              void* d_out, int out_size, void* d_ws, size_t ws_size,
                              hipStream_t stream) {
    const int* stu_idx  = (const int*)d_in[0];
    const int* item_idx = (const int*)d_in[1];
    const int* conc_idx = (const int*)d_in[2];
    const float* stu_fusion     = (const float*)d_in[3];
    const float* item_fusion    = (const float*)d_in[4];
    const float* concept_fusion = (const float*)d_in[5];
    const float* W_stu          = (const float*)d_in[6];
    const float* W_item         = (const float*)d_in[7];
    const float* w_pred         = (const float*)d_in[8];
    const float* b_pred         = (const float*)d_in[9];
    float* out = (float*)d_out;

    // workspace (_Float16): ESP | EIP | ECS | ECI | WH
    _Float16* ESP = (_Float16*)d_ws;
    _Float16* EIP = ESP + (size_t)NSTU * CNUM;
    _Float16* ECS = EIP + (size_t)NITEM * CNUM;
    _Float16* ECI = ECS + (size_t)NCONC * CNUM;
    _Float16* WH  = ECI + (size_t)NCONC * CNUM;

    proj_mfma<<<PROJ_BLKS, 256, 0, stream>>>(
        stu_fusion, item_fusion, concept_fusion, W_stu, W_item, w_pred,
        ESP, EIP, ECS, ECI, WH);

    edge_kernel<<<EDGE_BLKS, 256, 0, stream>>>(
        stu_idx, item_idx, (const int4*)conc_idx,
        ESP, EIP, ECS, ECI, WH, b_pred, out);
}